// Round 3
// baseline (4059.362 us; speedup 1.0000x reference)
//
#include <hip/hip_runtime.h>

// R17: remove the AGPR<->VGPR shuttle tax. R16 post-mortem: VGPR_Count=128
// with 208 live weight floats means the RA parked weights in AGPRs; the
// "v"-constrained v_pk_fma inline asm (VOP3P cannot read AGPRs on gfx950,
// R13 ground truth) then forced ~208 v_accvgpr_read per phase -- measured
// ~437 instr/phase vs ~290 expected, plus scratch traffic (WRITE_SIZE
// 8.7->26.7 MB). Fix: scalar fmaf matvec in plain C. With 1 seq/wave the
// live set is 208 weights + ~45 working ~= 253 <= 256, so under
// waves_per_eu(2) everything fits in arch VGPRs: no AGPRs, no shuttles,
// no spills. Scalar VALU also reads AGPRs directly on gfx90a+ if the RA
// still uses them -- either way the shuttle disappears.
//
// Numerics: two accumulators per gate (even-k / odd-k) reproduce the pk
// lane-x/lane-y summation order exactly -> bit-identical to R14/R15/R16.
//
// Carried forward: 1 seq/wave, 2 waves/SIMD (R16); z-row trick (lanes
// 51..54 compute LSTM2's x-side dot products in the gate-i slot); re-phased
// LSTM2; exp2-based activations with pre-scaled weights; bias folded into
// the k=51 slot (hrow[51]==1.0); branch-free warm loop with 64-step
// buffered input/output.

#define H1N  51
#define NP   26    // k-pairs: k=0..51; k=51 slot = bias (hrow[51]=1.0)
#define NQ   13    // k-quads for the b128 hrow broadcast reads
#define WAVE 64

typedef float v4f __attribute__((ext_vector_type(4)));

#define INV_LN2   1.44269504088896340736f
#define INV_LN2X2 2.88539008177792681472f

__device__ __forceinline__ float sigmoid_s(float xs) {   // input pre-scaled by 1/ln2
    return __builtin_amdgcn_rcpf(1.0f + __builtin_amdgcn_exp2f(-xs));
}
__device__ __forceinline__ float tanh_s2(float xs2) {    // input pre-scaled by 2/ln2
    float e = __builtin_amdgcn_exp2f(xs2);
    return fmaf(-2.0f, __builtin_amdgcn_rcpf(e + 1.0f), 1.0f);
}
__device__ __forceinline__ float tanh_nat(float x) {
    return tanh_s2(x * INV_LN2X2);
}
__device__ __forceinline__ float rdlane(float v, int k) {
    return __int_as_float(__builtin_amdgcn_readlane(__float_as_int(v), k));
}

__global__ __attribute__((amdgpu_flat_work_group_size(64, 64),
                          amdgpu_waves_per_eu(2)))
void lstm_seq1s(const float* __restrict__ input,   // [B, T]
                const float* __restrict__ W_ih1,   // [204, 1]
                const float* __restrict__ W_hh1,   // [204, 51]
                const float* __restrict__ b_ih1,   // [204]
                const float* __restrict__ b_hh1,   // [204]
                const float* __restrict__ W_ih2,   // [4, 51]
                const float* __restrict__ W_hh2,   // [4, 1]
                const float* __restrict__ b_ih2,   // [4]
                const float* __restrict__ b_hh2,   // [4]
                float* __restrict__ out,           // [B, T+F]
                int T, int TF)
{
    const int j   = threadIdx.x;
    const bool jv = (j < H1N);
    const int jj  = jv ? j : 0;
    const float m = jv ? 1.0f : 0.0f;
    const bool isz = (j >= H1N) && (j < H1N + 4);   // z-row lanes 51..54
    const int  q   = isz ? (j - H1N) : 0;
    const float mz = isz ? 1.0f : 0.0f;
    const float s2q = (q == 2) ? INV_LN2X2 : INV_LN2;  // LSTM2 gate scale

    const int s = blockIdx.x;                          // one sequence per wave

    const int r_i = jj, r_f = H1N + jj, r_g = 2*H1N + jj, r_o = 3*H1N + jj;
    const float s_i = INV_LN2, s_f = INV_LN2, s_g = INV_LN2X2, s_o = INV_LN2;

    __shared__ __align__(16) float hrow[WAVE];
    __shared__ __align__(16) float zb[4];

    // All four gate weight tables in registers: even-k and odd-k halves
    // (208 scalars). Lanes<51 = the 4 gate rows of unit j (scaled; bias
    // folded into the k=51 slot); lanes 51..54 carry W_ih2 row q (gate-i).
    float wI0[NP], wI1[NP], wF0[NP], wF1[NP];
    float wG0[NP], wG1[NP], wO0[NP], wO1[NP];
#pragma unroll
    for (int kk = 0; kk < NP; ++kk) {
        const int k0 = 2*kk, k1 = k0 + 1;
        wI0[kk] = m*s_i*W_hh1[r_i*H1N + k0] + mz*s2q*W_ih2[q*H1N + k0];
        wF0[kk] = m*s_f*W_hh1[r_f*H1N + k0];
        wG0[kk] = m*s_g*W_hh1[r_g*H1N + k0];
        wO0[kk] = m*s_o*W_hh1[r_o*H1N + k0];
        if (k1 < H1N) {
            wI1[kk] = m*s_i*W_hh1[r_i*H1N + k1] + mz*s2q*W_ih2[q*H1N + k1];
            wF1[kk] = m*s_f*W_hh1[r_f*H1N + k1];
            wG1[kk] = m*s_g*W_hh1[r_g*H1N + k1];
            wO1[kk] = m*s_o*W_hh1[r_o*H1N + k1];
        } else {   // k1 == 51: bias slot (hrow[51] == 1.0); z-rows get 0
            wI1[kk] = m*s_i*(b_ih1[r_i] + b_hh1[r_i]);
            wF1[kk] = m*s_f*(b_ih1[r_f] + b_hh1[r_f]);
            wG1[kk] = m*s_g*(b_ih1[r_g] + b_hh1[r_g]);
            wO1[kk] = m*s_o*(b_ih1[r_o] + b_hh1[r_o]);
        }
    }
    // One-time pin: anchors the masked-scaled weights as computed (blocks
    // remat-from-global in the loop), without in-loop round-trips.
#pragma unroll
    for (int kk = 0; kk < NP; ++kk) {
        asm volatile("" : "+v"(wI0[kk]), "+v"(wI1[kk]), "+v"(wF0[kk]), "+v"(wF1[kk]));
        asm volatile("" : "+v"(wG0[kk]), "+v"(wG1[kk]), "+v"(wO0[kk]), "+v"(wO1[kk]));
    }

    const float wx_i = m*s_i*W_ih1[r_i];
    const float wx_f = m*s_f*W_ih1[r_f];
    const float wx_g = m*s_g*W_ih1[r_g];
    const float wx_o = m*s_o*W_ih1[r_o];

    // LSTM2 thread-uniform scalars (SGPRs), pre-scaled.
    const float wh2_0 = INV_LN2*W_hh2[0], wh2_1 = INV_LN2*W_hh2[1];
    const float wh2_2 = INV_LN2X2*W_hh2[2], wh2_3 = INV_LN2*W_hh2[3];
    const float b2_0 = INV_LN2*(b_ih2[0] + b_hh2[0]), b2_1 = INV_LN2*(b_ih2[1] + b_hh2[1]);
    const float b2_2 = INV_LN2X2*(b_ih2[2] + b_hh2[2]), b2_3 = INV_LN2*(b_ih2[3] + b_hh2[3]);

    hrow[j] = (j == H1N) ? 1.0f : 0.0f;   // h1(-1)=0; [51]=1.0 (bias lane)

    float c1 = 0.0f, h2 = 0.0f, c2 = 0.0f;

    const float* __restrict__ xrow = input + (long)s * T;
    float* __restrict__ orow = out + (long)s * TF;

    float xbuf = 0.0f, obuf = 0.0f;

    // One pipeline phase: matvec on h1(n-1) -> [LSTM2 step n-1] -> [finish
    // LSTM1 step n]. xmode/do_l2/do_fin are compile-time at each call site.
    auto phase = [&](float xin, int xmode, int do_l2, int do_fin, int tt) {
        float aIe = 0.0f, aIo = 0.0f, aFe = 0.0f, aFo = 0.0f;
        float aGe = 0.0f, aGo = 0.0f, aOe = 0.0f, aOo = 0.0f;
#pragma unroll
        for (int kq = 0; kq < NQ; ++kq) {
            const v4f h4 = *(const v4f*)&hrow[4*kq];   // ds_read_b128 bcast
            const int p0 = 2*kq, p1 = p0 + 1;
            aIe = fmaf(wI0[p0], h4.x, aIe);
            aFe = fmaf(wF0[p0], h4.x, aFe);
            aGe = fmaf(wG0[p0], h4.x, aGe);
            aOe = fmaf(wO0[p0], h4.x, aOe);
            aIo = fmaf(wI1[p0], h4.y, aIo);
            aFo = fmaf(wF1[p0], h4.y, aFo);
            aGo = fmaf(wG1[p0], h4.y, aGo);
            aOo = fmaf(wO1[p0], h4.y, aOo);
            aIe = fmaf(wI0[p1], h4.z, aIe);
            aFe = fmaf(wF0[p1], h4.z, aFe);
            aGe = fmaf(wG0[p1], h4.z, aGe);
            aOe = fmaf(wO0[p1], h4.z, aOe);
            aIo = fmaf(wI1[p1], h4.w, aIo);
            aFo = fmaf(wF1[p1], h4.w, aFo);
            aGo = fmaf(wG1[p1], h4.w, aGo);
            aOo = fmaf(wO1[p1], h4.w, aOo);
        }
        const float mI = aIe + aIo;
        if (isz) zb[q] = mI;                  // z_q(n-1) from the z-row lanes
        const float mF = aFe + aFo, mG = aGe + aGo, mO = aOe + aOo;

        if (do_l2) {                          // LSTM2 step n-1 (wave-uniform)
            const float4 z = *(const float4*)zb;   // ds_read_b128 bcast
            const float g2i = sigmoid_s(fmaf(wh2_0, h2, b2_0 + z.x));
            const float g2f = sigmoid_s(fmaf(wh2_1, h2, b2_1 + z.y));
            const float g2g = tanh_s2 (fmaf(wh2_2, h2, b2_2 + z.z));
            const float g2o = sigmoid_s(fmaf(wh2_3, h2, b2_3 + z.w));
            c2 = fmaf(g2f, c2, g2i * g2g);
            h2 = g2o * tanh_nat(c2);
            obuf = (j == (tt & 63)) ? h2 : obuf;   // predicated pack
        }
        if (do_fin) {                         // finish LSTM1 step n
            const float x = (xmode == 0) ? xin : h2;
            const float gi = sigmoid_s(fmaf(wx_i, x, mI));
            const float gf = sigmoid_s(fmaf(wx_f, x, mF));
            const float gg = tanh_s2 (fmaf(wx_g, x, mG));
            const float go = sigmoid_s(fmaf(wx_o, x, mO));
            c1 = fmaf(gf, c1, gi * gg);
            const float h1 = go * tanh_nat(c1);
            if (jv) hrow[j] = h1;             // publish h1(n)
        }
    };

    // ---- Prologue: iteration n=0 (no LSTM2 yet) ----
    xbuf = xrow[j];
    phase(rdlane(xbuf, 0), 0, 0, 1, 0);

    // ---- Warm loop: n = 1..T-1 (x from input) ----
    for (int n = 1; n < T; ++n) {
        if ((n & 63) == 0) xbuf = xrow[n + j];
        const float x = rdlane(xbuf, n & 63);
        phase(x, 0, 1, 1, n - 1);
        if ((n & 63) == 0) orow[n - 64 + j] = obuf;   // flush tt = n-64..n-1
    }

    // ---- Boundary: n = T (LSTM2 for T-1; first feedback step x=h2) ----
    phase(0.0f, 1, 1, 1, T - 1);
    orow[T - 64 + j] = obuf;                  // flush tt = T-64..T-1

    // ---- Future loop: n = T+1..TF-1 (x = h2 feedback) ----
    for (int n = T + 1; n < TF; ++n)
        phase(0.0f, 1, 1, 1, n - 1);

    // ---- Drain: n = TF (LSTM2 for TF-1 only) ----
    phase(0.0f, 1, 1, 0, TF - 1);
    orow[TF - 64 + j] = obuf;                 // flush tt = TF-64..TF-1
}

extern "C" void kernel_launch(void* const* d_in, const int* in_sizes, int n_in,
                              void* d_out, int out_size, void* d_ws, size_t ws_size,
                              hipStream_t stream) {
    const float* input = (const float*)d_in[0];
    const float* W_ih1 = (const float*)d_in[1];
    const float* W_hh1 = (const float*)d_in[2];
    const float* b_ih1 = (const float*)d_in[3];
    const float* b_hh1 = (const float*)d_in[4];
    const float* W_ih2 = (const float*)d_in[5];
    const float* W_hh2 = (const float*)d_in[6];
    const float* b_ih2 = (const float*)d_in[7];
    const float* b_hh2 = (const float*)d_in[8];
    float* out = (float*)d_out;

    const int B  = 2048;
    const int T  = in_sizes[0] / B;      // 1024
    const int TF = out_size   / B;       // 1088

    lstm_seq1s<<<dim3(B), dim3(WAVE), 0, stream>>>(
        input, W_ih1, W_hh1, b_ih1, b_hh1, W_ih2, W_hh2, b_ih2, b_hh2,
        out, T, TF);
}